// Round 5
// baseline (6068.558 us; speedup 1.0000x reference)
//
#include <hip/hip_runtime.h>
#include <hip/hip_bf16.h>

#define P_TOT 65536
#define DIM   384
#define KCL   64
#define ITERS 10
#define APTS  256    // points per accum block
#define NACC  256    // # accum blocks (P_TOT/APTS)
#define ASTR  257    // padded LDS stride for transposed x-chunk (conflict-free)
#define ABUF  (32 * ASTR)

// ws (floats): centers[24576] | cnorm[64] | CW[24576]           (~196 KB)
// d_out scratch (floats), all dead before final_kernel:
//   [0, 65536)            labels (int)
//   [65536, +6291456)     partials[256][64][384]
//   then pcnt[256][64]

// ---- shared distance+label routine: one point per lane, acc[64] in VGPRs,
// A via LDS chunks (32 ds_read_b32, reused over 64 clusters), B via
// wave-uniform loads (scalar path, stays off the LDS/VALU-critical pipes).
__device__ __forceinline__ int point_label(const float* __restrict__ x,
                                           const float* __restrict__ centers,
                                           const float* __restrict__ cnorm,
                                           int p0, int tid, float* At) {
    float acc[64];
#pragma unroll
    for (int c = 0; c < 64; ++c) acc[c] = 0.f;

    // stage chunk 0 (transposed: At[k][tid], stride ASTR)
    {
        float4 rv[8];
#pragma unroll
        for (int q = 0; q < 8; ++q) {
            const int flat = q * 1024 + tid * 4;
            rv[q] = *(const float4*)(x + (size_t)(p0 + (flat >> 5)) * DIM + (flat & 31));
        }
#pragma unroll
        for (int q = 0; q < 8; ++q) {
            const int flat = q * 1024 + tid * 4;
            const int pt = flat >> 5, k = flat & 31;
            At[(k + 0) * ASTR + pt] = rv[q].x;
            At[(k + 1) * ASTR + pt] = rv[q].y;
            At[(k + 2) * ASTR + pt] = rv[q].z;
            At[(k + 3) * ASTR + pt] = rv[q].w;
        }
    }
    __syncthreads();

#pragma unroll 1
    for (int kt = 0; kt < 12; ++kt) {
        float* cur = At + (kt & 1) * ABUF;
        // prefetch next chunk into registers
        float4 rv[8];
        if (kt < 11) {
            const int k0n = (kt + 1) * 32;
#pragma unroll
            for (int q = 0; q < 8; ++q) {
                const int flat = q * 1024 + tid * 4;
                rv[q] = *(const float4*)(x + (size_t)(p0 + (flat >> 5)) * DIM + k0n + (flat & 31));
            }
        }
        // my point's 32 dims for this chunk
        float a[32];
#pragma unroll
        for (int k = 0; k < 32; ++k) a[k] = cur[k * ASTR + tid];

        const float* cb = centers + kt * 32;
#pragma unroll
        for (int c = 0; c < 64; ++c) {
            const float4* bp = (const float4*)(cb + c * DIM);
            float4 b0 = bp[0], b1 = bp[1], b2 = bp[2], b3 = bp[3];
            float4 b4 = bp[4], b5 = bp[5], b6 = bp[6], b7 = bp[7];
            float s = acc[c];
            s = fmaf(a[0],  b0.x, s); s = fmaf(a[1],  b0.y, s);
            s = fmaf(a[2],  b0.z, s); s = fmaf(a[3],  b0.w, s);
            s = fmaf(a[4],  b1.x, s); s = fmaf(a[5],  b1.y, s);
            s = fmaf(a[6],  b1.z, s); s = fmaf(a[7],  b1.w, s);
            s = fmaf(a[8],  b2.x, s); s = fmaf(a[9],  b2.y, s);
            s = fmaf(a[10], b2.z, s); s = fmaf(a[11], b2.w, s);
            s = fmaf(a[12], b3.x, s); s = fmaf(a[13], b3.y, s);
            s = fmaf(a[14], b3.z, s); s = fmaf(a[15], b3.w, s);
            s = fmaf(a[16], b4.x, s); s = fmaf(a[17], b4.y, s);
            s = fmaf(a[18], b4.z, s); s = fmaf(a[19], b4.w, s);
            s = fmaf(a[20], b5.x, s); s = fmaf(a[21], b5.y, s);
            s = fmaf(a[22], b5.z, s); s = fmaf(a[23], b5.w, s);
            s = fmaf(a[24], b6.x, s); s = fmaf(a[25], b6.y, s);
            s = fmaf(a[26], b6.z, s); s = fmaf(a[27], b6.w, s);
            s = fmaf(a[28], b7.x, s); s = fmaf(a[29], b7.y, s);
            s = fmaf(a[30], b7.z, s); s = fmaf(a[31], b7.w, s);
            acc[c] = s;
        }
        if (kt < 11) {
            float* nxt = At + ((kt + 1) & 1) * ABUF;
#pragma unroll
            for (int q = 0; q < 8; ++q) {
                const int flat = q * 1024 + tid * 4;
                const int pt = flat >> 5, k = flat & 31;
                nxt[(k + 0) * ASTR + pt] = rv[q].x;
                nxt[(k + 1) * ASTR + pt] = rv[q].y;
                nxt[(k + 2) * ASTR + pt] = rv[q].z;
                nxt[(k + 3) * ASTR + pt] = rv[q].w;
            }
        }
        __syncthreads();
    }

    float bv = 3.4e38f; int bc = 0;
#pragma unroll
    for (int c = 0; c < 64; ++c) {
        float d = cnorm[c] - 2.0f * acc[c];
        if (d < bv) { bv = d; bc = c; }  // strict <: lowest index wins ties
    }
    return bc;
}

// centers0 = points[:64]; cnorm[c] = ||center||^2
__global__ __launch_bounds__(384) void init_kernel(const float* __restrict__ x,
                                                   float* __restrict__ centers,
                                                   float* __restrict__ cnorm) {
    __shared__ float red[384];
    const int c = blockIdx.x, t = threadIdx.x;
    float v = x[(size_t)c * DIM + t];
    centers[(size_t)c * DIM + t] = v;
    red[t] = v * v;
    __syncthreads();
    if (t < 128) red[t] = red[t] + red[t + 128] + red[t + 256];
    __syncthreads();
    for (int s = 64; s > 0; s >>= 1) {
        if (t < s) red[t] += red[t + s];
        __syncthreads();
    }
    if (t == 0) cnorm[c] = red[0];
}

__global__ __launch_bounds__(256) void assign_kernel(const float* __restrict__ x,
                                                     const float* __restrict__ centers,
                                                     const float* __restrict__ cnorm,
                                                     int* __restrict__ labels) {
    __shared__ float At[2 * ABUF];
    const int tid = threadIdx.x;
    const int p0 = blockIdx.x * 256;
    const int bc = point_label(x, centers, cnorm, p0, tid, At);
    labels[p0 + tid] = bc;
}

// dim-parallel accumulation -> NON-atomic per-block partials
__global__ __launch_bounds__(384) void accum_kernel(const float* __restrict__ x,
                                                    const int* __restrict__ labels,
                                                    float* __restrict__ partials,
                                                    float* __restrict__ pcnt) {
    __shared__ float lsum[KCL * DIM];   // 96 KB
    __shared__ int   llab[APTS];
    __shared__ int   lcnt[KCL];
    const int t = threadIdx.x;
    for (int i = t; i < KCL * DIM; i += 384) lsum[i] = 0.f;
    if (t < KCL) lcnt[t] = 0;
    const int p0 = blockIdx.x * APTS;
    if (t < APTS) llab[t] = labels[p0 + t];
    __syncthreads();
    if (t < APTS) atomicAdd(&lcnt[llab[t]], 1);

    const float* xp = x + (size_t)p0 * DIM + t;
#pragma unroll 1
    for (int i = 0; i < APTS; i += 4) {
        const int l0 = llab[i + 0], l1 = llab[i + 1];
        const int l2 = llab[i + 2], l3 = llab[i + 3];
        const float v0 = xp[(size_t)(i + 0) * DIM];
        const float v1 = xp[(size_t)(i + 1) * DIM];
        const float v2 = xp[(size_t)(i + 2) * DIM];
        const float v3 = xp[(size_t)(i + 3) * DIM];
        lsum[l0 * DIM + t] += v0;
        lsum[l1 * DIM + t] += v1;
        lsum[l2 * DIM + t] += v2;
        lsum[l3 * DIM + t] += v3;
    }
    __syncthreads();
    float* pb = partials + (size_t)blockIdx.x * (KCL * DIM);
    for (int i = t; i < KCL * DIM; i += 384) pb[i] = lsum[i];
    if (t < KCL) pcnt[blockIdx.x * KCL + t] = (float)lcnt[t];
}

// reduce partials -> centers, cnorm
__global__ __launch_bounds__(384) void update_kernel(const float* __restrict__ partials,
                                                     const float* __restrict__ pcnt,
                                                     float* __restrict__ centers,
                                                     float* __restrict__ cnorm) {
    __shared__ float red[384];
    const int c = blockIdx.x, t = threadIdx.x;
    float s = 0.f;
#pragma unroll 4
    for (int b = 0; b < NACC; ++b) s += partials[(size_t)b * (KCL * DIM) + c * DIM + t];
    float n = 0.f;
#pragma unroll 4
    for (int b = 0; b < NACC; ++b) n += pcnt[b * KCL + c];
    float oldv = centers[(size_t)c * DIM + t];
    float nc = (n > 0.f) ? (s / n) : oldv;
    centers[(size_t)c * DIM + t] = nc;
    red[t] = nc * nc;
    __syncthreads();
    if (t < 128) red[t] = red[t] + red[t + 128] + red[t + 256];
    __syncthreads();
    for (int st = 64; st > 0; st >>= 1) {
        if (t < st) red[t] += red[t + st];
        __syncthreads();
    }
    if (t == 0) cnorm[c] = red[0];
}

// CW[c][j] = b[j] + sum_d centers[c][d] * W[j][d]
__global__ __launch_bounds__(384) void cw_kernel(const float* __restrict__ centers,
                                                 const float* __restrict__ W,
                                                 const float* __restrict__ b,
                                                 float* __restrict__ CW) {
    __shared__ float cs[DIM];
    const int c = blockIdx.x, j = threadIdx.x;
    cs[j] = centers[(size_t)c * DIM + j];
    __syncthreads();
    float acc = b[j];
    const float* wr = W + (size_t)j * DIM;
    for (int d4 = 0; d4 < 96; ++d4) {
        float4 v = *(const float4*)(wr + d4 * 4);
        acc += cs[d4 * 4 + 0] * v.x + cs[d4 * 4 + 1] * v.y
             + cs[d4 * 4 + 2] * v.z + cs[d4 * 4 + 3] * v.w;
    }
    CW[(size_t)c * DIM + j] = acc;
}

// fused final assignment + output write (never reads d_out -> no race)
__global__ __launch_bounds__(256) void final_kernel(const float* __restrict__ x,
                                                    const float* __restrict__ centers,
                                                    const float* __restrict__ cnorm,
                                                    const float* __restrict__ CW,
                                                    float* __restrict__ out) {
    __shared__ float At[2 * ABUF];
    __shared__ int   lab[256];
    const int tid = threadIdx.x;
    const int p0 = blockIdx.x * 256;
    const int bc = point_label(x, centers, cnorm, p0, tid, At);
    lab[tid] = bc;
    __syncthreads();
    // 256 points x 96 float4 = 24576 float4; 96 per thread, coalesced
#pragma unroll 4
    for (int r = 0; r < 96; ++r) {
        const int q = r * 256 + tid;
        const int pt = q / 96;
        const int jg = q - pt * 96;
        float4 v = *(const float4*)(CW + (size_t)lab[pt] * DIM + jg * 4);
        *(float4*)(out + (size_t)(p0 + pt) * DIM + jg * 4) = v;
    }
}

extern "C" void kernel_launch(void* const* d_in, const int* in_sizes, int n_in,
                              void* d_out, int out_size, void* d_ws, size_t ws_size,
                              hipStream_t stream) {
    const float* x = (const float*)d_in[0];  // fp32 (16,4096,384)
    const float* W = (const float*)d_in[1];  // fp32 (384,384)
    const float* b = (const float*)d_in[2];  // fp32 (384,)
    float* out = (float*)d_out;              // fp32 (16,4096,384)

    float* centers = (float*)d_ws;                 // 64*384
    float* cnorm   = centers + KCL * DIM;          // 64
    float* CW      = cnorm + KCL;                  // 64*384

    int*   labels   = (int*)d_out;                               // 256 KB
    float* partials = (float*)d_out + P_TOT;                     // 25.2 MB
    float* pcnt     = partials + (size_t)NACC * KCL * DIM;       // 64 KB

    init_kernel<<<KCL, 384, 0, stream>>>(x, centers, cnorm);
    for (int it = 0; it < ITERS; ++it) {
        assign_kernel<<<P_TOT / 256, 256, 0, stream>>>(x, centers, cnorm, labels);
        accum_kernel<<<NACC, 384, 0, stream>>>(x, labels, partials, pcnt);
        update_kernel<<<KCL, 384, 0, stream>>>(partials, pcnt, centers, cnorm);
    }
    cw_kernel<<<KCL, 384, 0, stream>>>(centers, W, b, CW);
    final_kernel<<<P_TOT / 256, 256, 0, stream>>>(x, centers, cnorm, CW, out);
}